// Round 12
// baseline (180.224 us; speedup 1.0000x reference)
//
#include <hip/hip_runtime.h>

// DenseFeatureNumericEmbedding: out[b, f*16+e] = sum_h relu(x[b,f]*W1[f,h]+b1[f,h])*W2[f,e,h] + b2[f,e]
// Piecewise-linear reformulation: per (f,e) the map x->emb is piecewise linear with
// breakpoints t_h = -b1/W1; tables hold slope/intercept per (f, interval, e).
//
// Ledger: R5a build (f,e)-parallel [-28us CONFIRMED]; R5b LDS->L2 reads [neutral];
// R8 grid swap [neutral]; R9 nt->plain store [neutral]; R10 fill-like dense stores
// [neutral]. Embed pinned ~80us (1.7TB/s effective writes) across 4 structurally
// different versions; fill does 6.5TB/s with the SAME store pattern but NO LOADS.
// R13 theory: vmcnt store-drain serialization. Loads and stores share the in-order
// vmcnt counter. Old loop order (stores of iter k-1 issued BEFORE loads of iter k,
// consumed immediately with nothing younger) forces s_waitcnt vmcnt(0) per iter ->
// every iteration waits for all prior STORE ACKS; with the HBM write queue backed
// up this serializes ~2000cy/iter across all waves (shared CU write port) ~= 78us.
// Explains neutrality of all data-path changes. R13 change: terminal stores.
//   RPB=4, 4096 blocks: phase0 digitize (VALU), phase1 ALL 16 table loads issued
//   together (waits are fine-grained vmcnt over loads only, no older stores),
//   phase2 FMA + 8 stores at kernel END with no subsequent waits -> stores drain
//   async under the next resident block's compute (4/CU, 16 sequential per CU).

#define F_   128
#define H_   64
#define E_   16
#define NROW 65            // intervals 0..64
#define GRS  32            // table row stride in floats (16 S + 16 T)
#define RPB  4             // batch rows per block
#define THREADS 256

typedef float vf4 __attribute__((ext_vector_type(4)));

// ---------------- build kernel: one wave per (feature, e) ----------------
__global__ __launch_bounds__(64) void build_tables(
    const float* __restrict__ W1, const float* __restrict__ B1,
    const float* __restrict__ W2, const float* __restrict__ B2,
    float* __restrict__ tbl, float* __restrict__ bps)
{
    const int f = blockIdx.x;   // 0..127
    const int e = blockIdx.y;   // 0..15
    const int h = threadIdx.x;  // 0..63

    __shared__ float ts_raw[H_];
    __shared__ float ts_sorted[H_];
    __shared__ float scS[H_];
    __shared__ float scT[H_];

    const float w1 = W1[f * H_ + h];
    const float bb = B1[f * H_ + h];
    const bool  slope = (w1 != 0.0f);
    const float t   = slope ? (-bb / w1) : __builtin_inff();
    const float sgn = slope ? (w1 > 0.0f ? 1.0f : -1.0f) : 0.0f;
    // active as x -> -inf: W1<0 terms (x*W1 -> +inf), plus constant-on terms (W1==0, b1>0)
    const bool act0 = (w1 < 0.0f) || (!slope && bb > 0.0f);

    ts_raw[h] = t;
    __syncthreads();
    int rank = 0;
    #pragma unroll
    for (int j = 0; j < H_; ++j) {
        float tj = ts_raw[j];
        rank += (tj < t || (tj == t && j < h)) ? 1 : 0;  // tie-break by index -> permutation
    }
    ts_sorted[rank] = t;
    __syncthreads();
    if (e == 0) bps[f * H_ + h] = ts_sorted[h];

    const float w2 = W2[(f * E_ + e) * H_ + h];
    // crossing t_h upward: W1>0 -> term turns ON (+), W1<0 -> OFF (-)
    const float dS = sgn * w1 * w2;
    const float dT = sgn * bb * w2;
    float bS = act0 ? w1 * w2 : 0.0f;
    float bT = act0 ? bb * w2 : 0.0f;
    #pragma unroll
    for (int d = 32; d; d >>= 1) { bS += __shfl_xor(bS, d); bT += __shfl_xor(bT, d); }

    scS[rank] = dS; scT[rank] = dT;  // scatter deltas into sorted order
    __syncthreads();
    float vS = scS[h], vT = scT[h];
    #pragma unroll
    for (int d = 1; d < 64; d <<= 1) {   // inclusive scan over sorted positions
        float uS = __shfl_up(vS, (unsigned)d);
        float uT = __shfl_up(vT, (unsigned)d);
        if (h >= d) { vS += uS; vT += uT; }
    }
    const float b2v = B2[f * E_ + e];
    float* row = tbl + ((size_t)f * NROW + (h + 1)) * GRS;  // interval k = h+1
    row[e]      = bS + vS;
    row[E_ + e] = bT + vT + b2v;
    if (h == 0) {
        float* r0 = tbl + (size_t)f * NROW * GRS;           // interval 0
        r0[e]      = bS;
        r0[E_ + e] = bT + b2v;
    }
}

// ---------------- main kernel: terminal-store pipeline ----------------
// el = tid&3 (e-quartet), fq = tid>>2 (0..63): thread owns features fq and fq+64.
// Per row, stores at orow + tid*16B and orow + 4096 + tid*16B (dense 1KB per wave).
// Structure: [x loads + digitize (VALU)] -> [all 16 table loads] -> [FMA + 8 stores,
// then s_endpgm]. No s_waitcnt ever follows a store.
__global__ __launch_bounds__(THREADS, 4) void embed_main(
    const float* __restrict__ x, const float* __restrict__ tbl,
    const float* __restrict__ bps, float* __restrict__ out)
{
    const int tid = threadIdx.x;
    const int el  = tid & 3;
    const int fq  = tid >> 2;
    const int fA  = fq;
    const int fB  = fq + 64;
    const int r0  = blockIdx.x * RPB;

    // ---- phase 0a: x loads (independent 64B-segment wave-loads) ----
    float xa[RPB], xb[RPB];
    #pragma unroll
    for (int i = 0; i < RPB; ++i) {
        xa[i] = x[(size_t)(r0 + i) * F_ + fA];
        xb[i] = x[(size_t)(r0 + i) * F_ + fB];
    }

    // this lane's quarter (16) of each feature's 64 sorted breakpoints (dies after digitize)
    float4 bpA[4], bpB[4];
    #pragma unroll
    for (int i = 0; i < 4; ++i) {
        bpA[i] = *(const float4*)(bps + (size_t)fA * H_ + el * 16 + 4 * i);
        bpB[i] = *(const float4*)(bps + (size_t)fB * H_ + el * 16 + 4 * i);
    }

    // ---- phase 0b: digitize all rows (pure VALU; order-independent count) ----
    int ca[RPB], cb[RPB];
    #pragma unroll
    for (int i = 0; i < RPB; ++i) {
        int a = 0, b = 0;
        #pragma unroll
        for (int j = 0; j < 4; ++j) {
            a += (bpA[j].x <= xa[i]) ? 1 : 0;
            a += (bpA[j].y <= xa[i]) ? 1 : 0;
            a += (bpA[j].z <= xa[i]) ? 1 : 0;
            a += (bpA[j].w <= xa[i]) ? 1 : 0;
            b += (bpB[j].x <= xb[i]) ? 1 : 0;
            b += (bpB[j].y <= xb[i]) ? 1 : 0;
            b += (bpB[j].z <= xb[i]) ? 1 : 0;
            b += (bpB[j].w <= xb[i]) ? 1 : 0;
        }
        // combine across the 4 el-lanes (lane bits 0-1; they share f and x)
        a += __shfl_xor(a, 1);  b += __shfl_xor(b, 1);
        a += __shfl_xor(a, 2);  b += __shfl_xor(b, 2);
        ca[i] = a; cb[i] = b;
    }

    // ---- phase 1: issue ALL table loads together (no older stores on vmcnt) ----
    const float* tA = tbl + (size_t)fA * NROW * GRS;
    const float* tB = tbl + (size_t)fB * NROW * GRS;
    float4 SA[RPB], TA[RPB], SB[RPB], TB[RPB];
    #pragma unroll
    for (int i = 0; i < RPB; ++i) {
        const float* rowA = tA + (size_t)ca[i] * GRS + el * 4;
        const float* rowB = tB + (size_t)cb[i] * GRS + el * 4;
        SA[i] = *(const float4*)(rowA);
        TA[i] = *(const float4*)(rowA + E_);
        SB[i] = *(const float4*)(rowB);
        TB[i] = *(const float4*)(rowB + E_);
    }

    // ---- phase 2: FMA + terminal stores (nothing waits on these) ----
    #pragma unroll
    for (int i = 0; i < RPB; ++i) {
        vf4 oA, oB;
        oA.x = fmaf(SA[i].x, xa[i], TA[i].x);
        oA.y = fmaf(SA[i].y, xa[i], TA[i].y);
        oA.z = fmaf(SA[i].z, xa[i], TA[i].z);
        oA.w = fmaf(SA[i].w, xa[i], TA[i].w);
        oB.x = fmaf(SB[i].x, xb[i], TB[i].x);
        oB.y = fmaf(SB[i].y, xb[i], TB[i].y);
        oB.z = fmaf(SB[i].z, xb[i], TB[i].z);
        oB.w = fmaf(SB[i].w, xb[i], TB[i].w);
        float* orow = out + (size_t)(r0 + i) * (F_ * E_);
        *(vf4*)(orow + tid * 4)        = oA;   // bytes [tid*16, +16) of row
        *(vf4*)(orow + 1024 + tid * 4) = oB;   // bytes [4096 + tid*16, +16)
    }
}

extern "C" void kernel_launch(void* const* d_in, const int* in_sizes, int n_in,
                              void* d_out, int out_size, void* d_ws, size_t ws_size,
                              hipStream_t stream) {
    const float* x  = (const float*)d_in[0];
    const float* W1 = (const float*)d_in[1];
    const float* b1 = (const float*)d_in[2];
    const float* W2 = (const float*)d_in[3];
    const float* b2 = (const float*)d_in[4];
    float* out = (float*)d_out;
    const int B = in_sizes[0] / F_;     // 16384

    // workspace: table 128*65*32 floats (1.02 MB) + sorted breakpoints 128*64 floats (32 KB)
    float* tbl = (float*)d_ws;
    float* bps = tbl + (size_t)F_ * NROW * GRS;

    build_tables<<<dim3(F_, E_), 64, 0, stream>>>(W1, b1, W2, b2, tbl, bps);
    embed_main<<<B / RPB, THREADS, 0, stream>>>(x, tbl, bps, out);  // 4096 blocks, 4/CU
}